// Round 1
// baseline (2981.494 us; speedup 1.0000x reference)
//
#include <hip/hip_runtime.h>

// GCN forward: x[50000,256] -> enc(256->128)+lrelu -> 2x GCNConv(128->128)+lrelu -> dec(128->64)
// All f32. edge_index int32, src = ei[0:E), dst = ei[E:2E). Self-loops added with weight dinv[i]^2.

constexpr int HID = 128;
constexpr float NEG = 0.1f;

__device__ __forceinline__ float lrelu(float v) { return v > 0.f ? v : v * NEG; }

__global__ __launch_bounds__(256) void k_deg(const int* __restrict__ dst, int E,
                                             float* __restrict__ deg) {
  int i = blockIdx.x * 256 + threadIdx.x;
  if (i < E) unsafeAtomicAdd(&deg[dst[i]], 1.0f);
}

__global__ __launch_bounds__(256) void k_dinv(float* __restrict__ deg, int N) {
  int i = blockIdx.x * 256 + threadIdx.x;
  if (i < N) deg[i] = rsqrtf(deg[i] + 1.0f);  // +1 for self-loop
}

// C1 = act(A@W + bias)  (single store), or DUAL: C1 = (A@W)*dinv[row], C2 = C1*dinv[row]
// A: [M,K] row-major, W: [K,BN] row-major. BM=64 rows/block, BK=32.
template <int BN, int TM, int TN, bool BIAS, bool ACT, bool DUAL>
__global__ __launch_bounds__(256) void k_gemm(const float* __restrict__ A,
                                              const float* __restrict__ W,
                                              const float* __restrict__ bias,
                                              const float* __restrict__ dinv,
                                              float* __restrict__ C1,
                                              float* __restrict__ C2, int M, int K) {
  constexpr int BM = 64, BK = 32;
  constexpr int CT = BN / TN;  // threads along cols; CT * (BM/TM) == 256
  __shared__ float As[BK][BM + 4];  // stride 68 floats = 272B (16B aligned), conflict-light
  __shared__ float Bs[BK][BN];
  const int tid = threadIdx.x;
  const int row0 = blockIdx.x * BM;
  const int tx = tid % CT, ty = tid / CT;
  float acc[TM][TN] = {};

  for (int k0 = 0; k0 < K; k0 += BK) {
    // stage A tile (transposed into LDS): BM*BK floats, float4 global loads
#pragma unroll
    for (int t = 0; t < (BM * BK) / 1024; ++t) {
      int f = tid + t * 256;       // float4 index over [BM][BK/4]
      int r = f >> 3;              // BK/4 == 8
      int kq = f & 7;
      float4 v = make_float4(0.f, 0.f, 0.f, 0.f);
      int gr = row0 + r;
      if (gr < M) v = *(const float4*)&A[(size_t)gr * K + k0 + kq * 4];
      As[kq * 4 + 0][r] = v.x;
      As[kq * 4 + 1][r] = v.y;
      As[kq * 4 + 2][r] = v.z;
      As[kq * 4 + 3][r] = v.w;
    }
    // stage B tile: BK*BN floats
#pragma unroll
    for (int t = 0; t < (BK * BN) / 1024; ++t) {
      int f = tid + t * 256;
      int kr = f / (BN / 4);
      int cq = f % (BN / 4);
      *(float4*)&Bs[kr][cq * 4] = *(const float4*)&W[(size_t)(k0 + kr) * BN + cq * 4];
    }
    __syncthreads();
#pragma unroll
    for (int kk = 0; kk < BK; ++kk) {
      float a[TM], b[TN];
      const float4* ap = (const float4*)&As[kk][ty * TM];
#pragma unroll
      for (int i = 0; i < TM / 4; ++i) ((float4*)a)[i] = ap[i];
      const float4* bp = (const float4*)&Bs[kk][tx * TN];
#pragma unroll
      for (int j = 0; j < TN / 4; ++j) ((float4*)b)[j] = bp[j];
#pragma unroll
      for (int i = 0; i < TM; ++i)
#pragma unroll
        for (int j = 0; j < TN; ++j) acc[i][j] = fmaf(a[i], b[j], acc[i][j]);
    }
    __syncthreads();
  }

  // epilogue (TN==4 -> float4 stores). For DUAL, C2 may alias A: each block only
  // reads its own 64 rows (all reads done above), so in-place is safe.
#pragma unroll
  for (int i = 0; i < TM; ++i) {
    int gr = row0 + ty * TM + i;
    if (gr >= M) continue;
    float4 v;
    float* vp = (float*)&v;
#pragma unroll
    for (int j = 0; j < TN; ++j) {
      float u = acc[i][j];
      if (BIAS) u += bias[tx * TN + j];
      if (ACT) u = lrelu(u);
      vp[j] = u;
    }
    if (DUAL) {
      float dv = dinv[gr];
      float4 s1 = make_float4(v.x * dv, v.y * dv, v.z * dv, v.w * dv);
      *(float4*)&C1[(size_t)gr * BN + tx * TN] = s1;
      float4 s2 = make_float4(s1.x * dv, s1.y * dv, s1.z * dv, s1.w * dv);
      *(float4*)&C2[(size_t)gr * BN + tx * TN] = s2;
    } else {
      *(float4*)&C1[(size_t)gr * BN + tx * TN] = v;
    }
  }
}

// 32 lanes per edge; t is pre-scaled by dinv[src], so weight = dinv[dst].
__global__ __launch_bounds__(256) void k_scatter(const int* __restrict__ src,
                                                 const int* __restrict__ dst, int E,
                                                 const float* __restrict__ dinv,
                                                 const float* __restrict__ t,
                                                 float* __restrict__ agg) {
  int g = (blockIdx.x * 256 + threadIdx.x) >> 5;
  int lane = threadIdx.x & 31;
  if (g >= E) return;
  int s = src[g], d = dst[g];
  float w = dinv[d];
  float4 v = ((const float4*)(t + (size_t)s * HID))[lane];
  float* o = agg + (size_t)d * HID + lane * 4;
  unsafeAtomicAdd(o + 0, v.x * w);
  unsafeAtomicAdd(o + 1, v.y * w);
  unsafeAtomicAdd(o + 2, v.z * w);
  unsafeAtomicAdd(o + 3, v.w * w);
}

__global__ __launch_bounds__(256) void k_act(float* __restrict__ h,
                                             const float* __restrict__ bias, int total4) {
  int i = blockIdx.x * 256 + threadIdx.x;
  if (i >= total4) return;
  float4 v = ((const float4*)h)[i];
  int c = (i & (HID / 4 - 1)) << 2;
  const float4 b = *(const float4*)&bias[c];
  v.x = lrelu(v.x + b.x);
  v.y = lrelu(v.y + b.y);
  v.z = lrelu(v.z + b.z);
  v.w = lrelu(v.w + b.w);
  ((float4*)h)[i] = v;
}

extern "C" void kernel_launch(void* const* d_in, const int* in_sizes, int n_in,
                              void* d_out, int out_size, void* d_ws, size_t ws_size,
                              hipStream_t stream) {
  const float* x = (const float*)d_in[0];
  const int* ei = (const int*)d_in[1];
  const float* enc_W = (const float*)d_in[2];
  const float* enc_b = (const float*)d_in[3];
  const float* conv_W = (const float*)d_in[4];
  const float* conv_b = (const float*)d_in[5];
  const float* dec_W = (const float*)d_in[6];
  const float* dec_b = (const float*)d_in[7];
  float* out = (float*)d_out;

  const int IN_DIM = 256;
  const int N = in_sizes[0] / IN_DIM;  // 50000
  const int E = in_sizes[1] / 2;       // 800000
  const int* src = ei;
  const int* dst = ei + E;

  char* wp = (char*)d_ws;
  float* dinv = (float*)wp;
  size_t off = (((size_t)N * 4) + 255) & ~(size_t)255;
  float* h = (float*)(wp + off);          // N*128 floats (also the agg buffer)
  float* t = h + (size_t)N * HID;         // N*128 floats

  // normalization
  hipMemsetAsync(dinv, 0, (size_t)N * sizeof(float), stream);
  k_deg<<<(E + 255) / 256, 256, 0, stream>>>(dst, E, dinv);
  k_dinv<<<(N + 255) / 256, 256, 0, stream>>>(dinv, N);

  const int gm = (N + 63) / 64;

  // encoder: h = lrelu(x @ enc_W + enc_b)
  k_gemm<128, 8, 4, true, true, false>
      <<<gm, 256, 0, stream>>>(x, enc_W, enc_b, nullptr, h, nullptr, N, IN_DIM);

  for (int l = 0; l < 2; ++l) {
    // t = (h @ W) * dinv[row];  h <- t * dinv[row]  (self-loop init, in-place)
    k_gemm<128, 8, 4, false, false, true>
        <<<gm, 256, 0, stream>>>(h, conv_W + (size_t)l * HID * HID, nullptr, dinv, t, h,
                                 N, HID);
    // h[d] += t[s] * dinv[d]
    k_scatter<<<(E + 7) / 8, 256, 0, stream>>>(src, dst, E, dinv, t, h);
    // h = lrelu(h + b)
    k_act<<<(N * (HID / 4) + 255) / 256, 256, 0, stream>>>(
        h, conv_b + (size_t)l * HID, N * (HID / 4));
  }

  // decoder: out = h @ dec_W + dec_b
  k_gemm<64, 4, 4, true, false, false>
      <<<gm, 256, 0, stream>>>(h, dec_W, dec_b, nullptr, out, nullptr, N, HID);
}

// Round 2
// 429.307 us; speedup vs baseline: 6.9449x; 6.9449x over previous
//
#include <hip/hip_runtime.h>

// GCN forward: x[50000,256] -> enc(256->128)+lrelu -> 2x GCNConv(128->128)+lrelu -> dec(128->64)
// All f32. edge_index int32, src = ei[0:E), dst = ei[E:2E).
// Aggregation strategy: build CSR over dst per call, gather (no f32 atomics).
// Self-loop term (t*dinv^2) is written into h by the GEMM epilogue (DUAL mode).

constexpr int HID = 128;
constexpr float NEG = 0.1f;

__device__ __forceinline__ float lrelu(float v) { return v > 0.f ? v : v * NEG; }

// ---- degree / normalization ----
__global__ __launch_bounds__(256) void k_deg(const int* __restrict__ dst, int E,
                                             int* __restrict__ deg) {
  int i = blockIdx.x * 256 + threadIdx.x;
  if (i < E) atomicAdd(&deg[dst[i]], 1);
}

__global__ __launch_bounds__(256) void k_dinv(const int* __restrict__ deg,
                                              float* __restrict__ dinv, int N) {
  int i = blockIdx.x * 256 + threadIdx.x;
  if (i < N) dinv[i] = rsqrtf((float)deg[i] + 1.0f);  // +1 for self-loop
}

// ---- exclusive prefix scan over deg -> rowptr (3 kernels) ----
__global__ __launch_bounds__(256) void k_scan1(const int* __restrict__ deg, int N,
                                               int* __restrict__ rowptr,
                                               int* __restrict__ bsum) {
  __shared__ int s[256];
  int i = blockIdx.x * 256 + threadIdx.x;
  int v = (i < N) ? deg[i] : 0;
  s[threadIdx.x] = v;
  __syncthreads();
#pragma unroll
  for (int off = 1; off < 256; off <<= 1) {
    int t = (threadIdx.x >= off) ? s[threadIdx.x - off] : 0;
    __syncthreads();
    s[threadIdx.x] += t;
    __syncthreads();
  }
  if (i < N) rowptr[i] = s[threadIdx.x] - v;  // exclusive
  if (threadIdx.x == 255) bsum[blockIdx.x] = s[255];
}

__global__ __launch_bounds__(256) void k_scan2(const int* __restrict__ bsum,
                                               int* __restrict__ boff, int nb) {
  __shared__ int s[256];
  int i = threadIdx.x;
  int v = (i < nb) ? bsum[i] : 0;
  s[i] = v;
  __syncthreads();
#pragma unroll
  for (int off = 1; off < 256; off <<= 1) {
    int t = (i >= off) ? s[i - off] : 0;
    __syncthreads();
    s[i] += t;
    __syncthreads();
  }
  if (i < nb) boff[i] = s[i] - v;
}

__global__ __launch_bounds__(256) void k_scan3(int* __restrict__ rowptr,
                                               const int* __restrict__ boff, int N) {
  int i = blockIdx.x * 256 + threadIdx.x;
  if (i < N) rowptr[i] += boff[blockIdx.x];
}

// ---- CSR fill: eidx[rowptr[d] + k] = src of k-th incoming edge of d ----
__global__ __launch_bounds__(256) void k_fill(const int* __restrict__ src,
                                              const int* __restrict__ dst, int E,
                                              const int* __restrict__ rowptr,
                                              int* __restrict__ cursor,
                                              int* __restrict__ eidx) {
  int e = blockIdx.x * 256 + threadIdx.x;
  if (e >= E) return;
  int d = dst[e];
  int pos = atomicAdd(&cursor[d], 1);
  eidx[rowptr[d] + pos] = src[e];
}

// ---- gather aggregation: h[d] = lrelu(h_self[d] + dinv[d] * sum_e t[src_e] + b) ----
// 32 lanes (float4) per node, 8 nodes per 256-block.
__global__ __launch_bounds__(256) void k_gather(const int* __restrict__ rowptr,
                                                const int* __restrict__ deg,
                                                const int* __restrict__ eidx,
                                                const float* __restrict__ t,
                                                const float* __restrict__ dinv,
                                                const float* __restrict__ bias,
                                                float* __restrict__ h, int N) {
  int node = (blockIdx.x * 256 + threadIdx.x) >> 5;
  int lane = threadIdx.x & 31;
  if (node >= N) return;
  const float4* t4 = (const float4*)t;
  int beg = rowptr[node];
  int d = deg[node];
  float4 acc = make_float4(0.f, 0.f, 0.f, 0.f);
  int e = 0;
  for (; e + 4 <= d; e += 4) {
    int s0 = eidx[beg + e + 0], s1 = eidx[beg + e + 1];
    int s2 = eidx[beg + e + 2], s3 = eidx[beg + e + 3];
    float4 v0 = t4[(size_t)s0 * 32 + lane];
    float4 v1 = t4[(size_t)s1 * 32 + lane];
    float4 v2 = t4[(size_t)s2 * 32 + lane];
    float4 v3 = t4[(size_t)s3 * 32 + lane];
    acc.x += (v0.x + v1.x) + (v2.x + v3.x);
    acc.y += (v0.y + v1.y) + (v2.y + v3.y);
    acc.z += (v0.z + v1.z) + (v2.z + v3.z);
    acc.w += (v0.w + v1.w) + (v2.w + v3.w);
  }
  for (; e < d; ++e) {
    int s = eidx[beg + e];
    float4 v = t4[(size_t)s * 32 + lane];
    acc.x += v.x; acc.y += v.y; acc.z += v.z; acc.w += v.w;
  }
  float w = dinv[node];
  float4 self = ((const float4*)h)[(size_t)node * 32 + lane];
  float4 b = ((const float4*)bias)[lane];
  float4 o;
  o.x = lrelu(self.x + w * acc.x + b.x);
  o.y = lrelu(self.y + w * acc.y + b.y);
  o.z = lrelu(self.z + w * acc.z + b.z);
  o.w = lrelu(self.w + w * acc.w + b.w);
  ((float4*)h)[(size_t)node * 32 + lane] = o;
}

// ---- dense GEMM (f32 vector ALU) ----
// C1 = act(A@W + bias), or DUAL: C1 = (A@W)*dinv[row], C2 = C1*dinv[row] (C2 may alias A).
template <int BN, int TM, int TN, bool BIAS, bool ACT, bool DUAL>
__global__ __launch_bounds__(256) void k_gemm(const float* __restrict__ A,
                                              const float* __restrict__ W,
                                              const float* __restrict__ bias,
                                              const float* __restrict__ dinv,
                                              float* __restrict__ C1,
                                              float* __restrict__ C2, int M, int K) {
  constexpr int BM = 64, BK = 32;
  constexpr int CT = BN / TN;  // threads along cols; CT * (BM/TM) == 256
  __shared__ float As[BK][BM + 4];
  __shared__ float Bs[BK][BN];
  const int tid = threadIdx.x;
  const int row0 = blockIdx.x * BM;
  const int tx = tid % CT, ty = tid / CT;
  float acc[TM][TN] = {};

  for (int k0 = 0; k0 < K; k0 += BK) {
#pragma unroll
    for (int t = 0; t < (BM * BK) / 1024; ++t) {
      int f = tid + t * 256;  // float4 index over [BM][BK/4]
      int r = f >> 3;         // BK/4 == 8
      int kq = f & 7;
      float4 v = make_float4(0.f, 0.f, 0.f, 0.f);
      int gr = row0 + r;
      if (gr < M) v = *(const float4*)&A[(size_t)gr * K + k0 + kq * 4];
      As[kq * 4 + 0][r] = v.x;
      As[kq * 4 + 1][r] = v.y;
      As[kq * 4 + 2][r] = v.z;
      As[kq * 4 + 3][r] = v.w;
    }
#pragma unroll
    for (int t = 0; t < (BK * BN) / 1024; ++t) {
      int f = tid + t * 256;
      int kr = f / (BN / 4);
      int cq = f % (BN / 4);
      *(float4*)&Bs[kr][cq * 4] = *(const float4*)&W[(size_t)(k0 + kr) * BN + cq * 4];
    }
    __syncthreads();
#pragma unroll
    for (int kk = 0; kk < BK; ++kk) {
      float a[TM], b[TN];
      const float4* ap = (const float4*)&As[kk][ty * TM];
#pragma unroll
      for (int i = 0; i < TM / 4; ++i) ((float4*)a)[i] = ap[i];
      const float4* bp = (const float4*)&Bs[kk][tx * TN];
#pragma unroll
      for (int j = 0; j < TN / 4; ++j) ((float4*)b)[j] = bp[j];
#pragma unroll
      for (int i = 0; i < TM; ++i)
#pragma unroll
        for (int j = 0; j < TN; ++j) acc[i][j] = fmaf(a[i], b[j], acc[i][j]);
    }
    __syncthreads();
  }

#pragma unroll
  for (int i = 0; i < TM; ++i) {
    int gr = row0 + ty * TM + i;
    if (gr >= M) continue;
    float4 v;
    float* vp = (float*)&v;
#pragma unroll
    for (int j = 0; j < TN; ++j) {
      float u = acc[i][j];
      if (BIAS) u += bias[tx * TN + j];
      if (ACT) u = lrelu(u);
      vp[j] = u;
    }
    if (DUAL) {
      float dv = dinv[gr];
      float4 s1 = make_float4(v.x * dv, v.y * dv, v.z * dv, v.w * dv);
      *(float4*)&C1[(size_t)gr * BN + tx * TN] = s1;
      float4 s2 = make_float4(s1.x * dv, s1.y * dv, s1.z * dv, s1.w * dv);
      *(float4*)&C2[(size_t)gr * BN + tx * TN] = s2;
    } else {
      *(float4*)&C1[(size_t)gr * BN + tx * TN] = v;
    }
  }
}

extern "C" void kernel_launch(void* const* d_in, const int* in_sizes, int n_in,
                              void* d_out, int out_size, void* d_ws, size_t ws_size,
                              hipStream_t stream) {
  const float* x = (const float*)d_in[0];
  const int* ei = (const int*)d_in[1];
  const float* enc_W = (const float*)d_in[2];
  const float* enc_b = (const float*)d_in[3];
  const float* conv_W = (const float*)d_in[4];
  const float* conv_b = (const float*)d_in[5];
  const float* dec_W = (const float*)d_in[6];
  const float* dec_b = (const float*)d_in[7];
  float* out = (float*)d_out;

  const int IN_DIM = 256;
  const int N = in_sizes[0] / IN_DIM;  // 50000
  const int E = in_sizes[1] / 2;       // 800000
  const int* src = ei;
  const int* dst = ei + E;
  const int nb = (N + 255) / 256;

  // workspace layout
  char* wp = (char*)d_ws;
  auto alloc = [&](size_t bytes) {
    void* p = wp;
    wp += (bytes + 255) & ~(size_t)255;
    return p;
  };
  int* deg = (int*)alloc((size_t)N * 4);
  int* cursor = (int*)alloc((size_t)N * 4);  // adjacent to deg: one memset covers both
  int* rowptr = (int*)alloc((size_t)N * 4);
  int* bsum = (int*)alloc(1024);
  int* boff = (int*)alloc(1024);
  int* eidx = (int*)alloc((size_t)E * 4);
  float* dinv = (float*)alloc((size_t)N * 4);
  float* h = (float*)alloc((size_t)N * HID * 4);
  float* t = (float*)alloc((size_t)N * HID * 4);

  // zero deg + cursor (contiguous, padded to 256B each)
  hipMemsetAsync(deg, 0, ((size_t)N * 4 + 255 & ~(size_t)255) * 2, stream);

  // normalization + CSR build
  k_deg<<<(E + 255) / 256, 256, 0, stream>>>(dst, E, deg);
  k_dinv<<<nb, 256, 0, stream>>>(deg, dinv, N);
  k_scan1<<<nb, 256, 0, stream>>>(deg, N, rowptr, bsum);
  k_scan2<<<1, 256, 0, stream>>>(bsum, boff, nb);
  k_scan3<<<nb, 256, 0, stream>>>(rowptr, boff, N);
  k_fill<<<(E + 255) / 256, 256, 0, stream>>>(src, dst, E, rowptr, cursor, eidx);

  const int gm = (N + 63) / 64;

  // encoder: h = lrelu(x @ enc_W + enc_b)
  k_gemm<128, 8, 4, true, true, false>
      <<<gm, 256, 0, stream>>>(x, enc_W, enc_b, nullptr, h, nullptr, N, IN_DIM);

  for (int l = 0; l < 2; ++l) {
    // t = (h @ W) * dinv[row];  h <- t * dinv[row]  (self-loop init, in-place)
    k_gemm<128, 8, 4, false, false, true>
        <<<gm, 256, 0, stream>>>(h, conv_W + (size_t)l * HID * HID, nullptr, dinv, t, h,
                                 N, HID);
    // h[d] = lrelu(h[d] + dinv[d] * sum_{e in in(d)} t[src_e] + b)
    k_gather<<<(N * 32 + 255) / 256, 256, 0, stream>>>(
        rowptr, deg, eidx, t, dinv, conv_b + (size_t)l * HID, h, N);
  }

  // decoder: out = h @ dec_W + dec_b
  k_gemm<64, 4, 4, true, false, false>
      <<<gm, 256, 0, stream>>>(h, dec_W, dec_b, nullptr, out, nullptr, N, HID);
}

// Round 3
// 401.645 us; speedup vs baseline: 7.4232x; 1.0689x over previous
//
#include <hip/hip_runtime.h>

// GCN forward: x[50000,256] -> enc(256->128)+lrelu -> 2x GCNConv(128->128)+lrelu -> dec(128->64)
// f32 in/out. GEMMs run on bf16 MFMA (16x16x32) with hi/lo split precision:
//   A @ W  ~=  A_hi@W_hi + A_hi@W_lo + A_lo@W_hi   (error ~2^-16 rel, f32-grade)
// Weights are pre-swizzled into MFMA fragment order once per call. A fragments are
// loaded straight from global f32 (8 contiguous floats/lane) and split in-register:
// no LDS, no barriers in the GEMM. Aggregation: CSR-over-dst + gather (no f32 atomics).

constexpr int HID = 128;
constexpr float NEG = 0.1f;

typedef __attribute__((ext_vector_type(8))) short short8;  // 8 bf16 (4 VGPRs)
typedef __attribute__((ext_vector_type(4))) float f32x4;   // MFMA C/D

__device__ __forceinline__ float lrelu(float v) { return v > 0.f ? v : v * NEG; }

__device__ __forceinline__ unsigned short f2bf(float f) {  // f32 -> bf16, RNE
  union { float f; unsigned u; } c; c.f = f;
  unsigned u = c.u;
  return (unsigned short)((u + 0x7fffu + ((u >> 16) & 1u)) >> 16);
}
__device__ __forceinline__ float bf2f(unsigned short h) {
  union { unsigned u; float f; } c; c.u = ((unsigned)h) << 16; return c.f;
}

// ---- degree / normalization ----
__global__ __launch_bounds__(256) void k_deg(const int* __restrict__ dst, int E,
                                             int* __restrict__ deg) {
  int i = blockIdx.x * 256 + threadIdx.x;
  if (i < E) atomicAdd(&deg[dst[i]], 1);
}

__global__ __launch_bounds__(256) void k_dinv(const int* __restrict__ deg,
                                              float* __restrict__ dinv, int N) {
  int i = blockIdx.x * 256 + threadIdx.x;
  if (i < N) dinv[i] = rsqrtf((float)deg[i] + 1.0f);  // +1 for self-loop
}

// ---- exclusive prefix scan over deg -> rowptr (3 kernels) ----
__global__ __launch_bounds__(256) void k_scan1(const int* __restrict__ deg, int N,
                                               int* __restrict__ rowptr,
                                               int* __restrict__ bsum) {
  __shared__ int s[256];
  int i = blockIdx.x * 256 + threadIdx.x;
  int v = (i < N) ? deg[i] : 0;
  s[threadIdx.x] = v;
  __syncthreads();
#pragma unroll
  for (int off = 1; off < 256; off <<= 1) {
    int t = (threadIdx.x >= off) ? s[threadIdx.x - off] : 0;
    __syncthreads();
    s[threadIdx.x] += t;
    __syncthreads();
  }
  if (i < N) rowptr[i] = s[threadIdx.x] - v;  // exclusive
  if (threadIdx.x == 255) bsum[blockIdx.x] = s[255];
}

__global__ __launch_bounds__(256) void k_scan2(const int* __restrict__ bsum,
                                               int* __restrict__ boff, int nb) {
  __shared__ int s[256];
  int i = threadIdx.x;
  int v = (i < nb) ? bsum[i] : 0;
  s[i] = v;
  __syncthreads();
#pragma unroll
  for (int off = 1; off < 256; off <<= 1) {
    int t = (i >= off) ? s[i - off] : 0;
    __syncthreads();
    s[i] += t;
    __syncthreads();
  }
  if (i < nb) boff[i] = s[i] - v;
}

__global__ __launch_bounds__(256) void k_scan3(int* __restrict__ rowptr,
                                               const int* __restrict__ boff, int N) {
  int i = blockIdx.x * 256 + threadIdx.x;
  if (i < N) rowptr[i] += boff[blockIdx.x];
}

// ---- CSR fill ----
__global__ __launch_bounds__(256) void k_fill(const int* __restrict__ src,
                                              const int* __restrict__ dst, int E,
                                              const int* __restrict__ rowptr,
                                              int* __restrict__ cursor,
                                              int* __restrict__ eidx) {
  int e = blockIdx.x * 256 + threadIdx.x;
  if (e >= E) return;
  int d = dst[e];
  int pos = atomicAdd(&cursor[d], 1);
  eidx[rowptr[d] + pos] = src[e];
}

// ---- weight swizzle: W[K][N] f32 -> fragment-ordered bf16 hi|lo ----
// wf index: ((ks*NT + nt)*64 + lane)*16 ; [0..7]=hi, [8..15]=lo
// lane holds B[k = ks*32 + (lane>>4)*8 + j][n = nt*16 + (lane&15)]
__global__ __launch_bounds__(256) void k_wconv(const float* __restrict__ W, int N,
                                               int KS, int NT,
                                               unsigned short* __restrict__ wf) {
  int idx = blockIdx.x * 256 + threadIdx.x;
  int total = KS * NT * 64;
  if (idx >= total) return;
  int lane = idx & 63, tile = idx >> 6;
  int nt = tile % NT, ks = tile / NT;
  int col = nt * 16 + (lane & 15);
  int krow = ks * 32 + (lane >> 4) * 8;
  unsigned short* o = wf + (size_t)idx * 16;
#pragma unroll
  for (int j = 0; j < 8; ++j) {
    float v = W[(size_t)(krow + j) * N + col];
    unsigned short hi = f2bf(v);
    o[j] = hi;
    o[8 + j] = f2bf(v - bf2f(hi));
  }
}

// ---- MFMA GEMM: C[M][NT*16] = A[M][K] @ W (+epilogue), no LDS ----
// MODE 0: C = lrelu(acc + bias)   (encoder)
// MODE 1: C = acc * dinv[row]     (conv -> t)
// MODE 2: C = acc + bias          (decoder)
template <int NT, int MODE>
__global__ __launch_bounds__(256) void k_mfma(const float* __restrict__ A,
                                              const unsigned short* __restrict__ wf,
                                              const float* __restrict__ bias,
                                              const float* __restrict__ dinv,
                                              float* __restrict__ C, int M, int K) {
  const int N = NT * 16;
  const int wave = threadIdx.x >> 6, lane = threadIdx.x & 63;
  const int q = lane >> 4, c16 = lane & 15;
  const int row0 = blockIdx.x * 64 + wave * 16;
  int arow = row0 + c16;
  if (arow >= M) arow = M - 1;  // clamp: only pollutes OOB C rows, which we don't store
  const float* ap = A + (size_t)arow * K + q * 8;
  f32x4 acc[NT];
#pragma unroll
  for (int i = 0; i < NT; ++i) acc[i] = (f32x4){0.f, 0.f, 0.f, 0.f};
  const int KS = K >> 5;
  for (int ks = 0; ks < KS; ++ks) {
    float av[8];
    *(float4*)&av[0] = *(const float4*)(ap + ks * 32);
    *(float4*)&av[4] = *(const float4*)(ap + ks * 32 + 4);
    short8 ahi, alo;
#pragma unroll
    for (int j = 0; j < 8; ++j) {
      unsigned short h = f2bf(av[j]);
      ahi[j] = (short)h;
      alo[j] = (short)f2bf(av[j] - bf2f(h));
    }
    const unsigned short* wp = wf + (size_t)ks * NT * 1024 + lane * 16;
#pragma unroll
    for (int nt = 0; nt < NT; ++nt) {
      short8 bhi = *(const short8*)(wp);
      short8 blo = *(const short8*)(wp + 8);
      acc[nt] = __builtin_amdgcn_mfma_f32_16x16x32_bf16(ahi, bhi, acc[nt], 0, 0, 0);
      acc[nt] = __builtin_amdgcn_mfma_f32_16x16x32_bf16(ahi, blo, acc[nt], 0, 0, 0);
      acc[nt] = __builtin_amdgcn_mfma_f32_16x16x32_bf16(alo, bhi, acc[nt], 0, 0, 0);
      wp += 1024;
    }
  }
  // C/D layout (verified m89): col = lane&15, row = (lane>>4)*4 + reg
#pragma unroll
  for (int nt = 0; nt < NT; ++nt) {
    int col = nt * 16 + c16;
    float bv = (MODE == 1) ? 0.f : bias[col];
#pragma unroll
    for (int r = 0; r < 4; ++r) {
      int gr = row0 + q * 4 + r;
      if (gr >= M) continue;
      float v = acc[nt][r];
      if (MODE == 0) v = lrelu(v + bv);
      else if (MODE == 1) v *= dinv[gr];
      else v += bv;
      C[(size_t)gr * N + col] = v;
    }
  }
}

// ---- gather aggregation: h[d] = lrelu((sum_e t[src_e] + t[d]) * dinv[d] + b) ----
// (t is pre-scaled by dinv[src]; self-loop term t[d]*dinv[d] folded in here)
__global__ __launch_bounds__(256) void k_gather(const int* __restrict__ rowptr,
                                                const int* __restrict__ deg,
                                                const int* __restrict__ eidx,
                                                const float* __restrict__ t,
                                                const float* __restrict__ dinv,
                                                const float* __restrict__ bias,
                                                float* __restrict__ h, int N) {
  int node = (blockIdx.x * 256 + threadIdx.x) >> 5;
  int lane = threadIdx.x & 31;
  if (node >= N) return;
  const float4* t4 = (const float4*)t;
  int beg = rowptr[node];
  int d = deg[node];
  float4 acc = make_float4(0.f, 0.f, 0.f, 0.f);
  int e = 0;
  for (; e + 4 <= d; e += 4) {
    int s0 = eidx[beg + e + 0], s1 = eidx[beg + e + 1];
    int s2 = eidx[beg + e + 2], s3 = eidx[beg + e + 3];
    float4 v0 = t4[(size_t)s0 * 32 + lane];
    float4 v1 = t4[(size_t)s1 * 32 + lane];
    float4 v2 = t4[(size_t)s2 * 32 + lane];
    float4 v3 = t4[(size_t)s3 * 32 + lane];
    acc.x += (v0.x + v1.x) + (v2.x + v3.x);
    acc.y += (v0.y + v1.y) + (v2.y + v3.y);
    acc.z += (v0.z + v1.z) + (v2.z + v3.z);
    acc.w += (v0.w + v1.w) + (v2.w + v3.w);
  }
  for (; e < d; ++e) {
    int s = eidx[beg + e];
    float4 v = t4[(size_t)s * 32 + lane];
    acc.x += v.x; acc.y += v.y; acc.z += v.z; acc.w += v.w;
  }
  float w = dinv[node];
  float4 ts = t4[(size_t)node * 32 + lane];
  float4 b = ((const float4*)bias)[lane];
  float4 o;
  o.x = lrelu((acc.x + ts.x) * w + b.x);
  o.y = lrelu((acc.y + ts.y) * w + b.y);
  o.z = lrelu((acc.z + ts.z) * w + b.z);
  o.w = lrelu((acc.w + ts.w) * w + b.w);
  ((float4*)h)[(size_t)node * 32 + lane] = o;
}

extern "C" void kernel_launch(void* const* d_in, const int* in_sizes, int n_in,
                              void* d_out, int out_size, void* d_ws, size_t ws_size,
                              hipStream_t stream) {
  const float* x = (const float*)d_in[0];
  const int* ei = (const int*)d_in[1];
  const float* enc_W = (const float*)d_in[2];
  const float* enc_b = (const float*)d_in[3];
  const float* conv_W = (const float*)d_in[4];
  const float* conv_b = (const float*)d_in[5];
  const float* dec_W = (const float*)d_in[6];
  const float* dec_b = (const float*)d_in[7];
  float* out = (float*)d_out;

  const int IN_DIM = 256;
  const int N = in_sizes[0] / IN_DIM;  // 50000
  const int E = in_sizes[1] / 2;       // 800000
  const int* src = ei;
  const int* dst = ei + E;
  const int nb = (N + 255) / 256;

  // workspace layout
  char* wp = (char*)d_ws;
  auto alloc = [&](size_t bytes) {
    void* p = wp;
    wp += (bytes + 255) & ~(size_t)255;
    return p;
  };
  int* deg = (int*)alloc((size_t)N * 4);
  int* cursor = (int*)alloc((size_t)N * 4);  // adjacent to deg: one memset covers both
  int* rowptr = (int*)alloc((size_t)N * 4);
  int* bsum = (int*)alloc(1024);
  int* boff = (int*)alloc(1024);
  int* eidx = (int*)alloc((size_t)E * 4);
  float* dinv = (float*)alloc((size_t)N * 4);
  float* h = (float*)alloc((size_t)N * HID * 4);
  float* t = (float*)alloc((size_t)N * HID * 4);
  unsigned short* wf_enc = (unsigned short*)alloc((size_t)8 * 8 * 64 * 16 * 2);   // K=256,N=128
  unsigned short* wf_c0 = (unsigned short*)alloc((size_t)4 * 8 * 64 * 16 * 2);    // K=128,N=128
  unsigned short* wf_c1 = (unsigned short*)alloc((size_t)4 * 8 * 64 * 16 * 2);
  unsigned short* wf_dec = (unsigned short*)alloc((size_t)4 * 4 * 64 * 16 * 2);   // K=128,N=64

  // zero deg + cursor (contiguous, each padded to 256B)
  hipMemsetAsync(deg, 0, (((size_t)N * 4 + 255) & ~(size_t)255) * 2, stream);

  // weight swizzles (tiny)
  k_wconv<<<16, 256, 0, stream>>>(enc_W, 128, 8, 8, wf_enc);
  k_wconv<<<8, 256, 0, stream>>>(conv_W, 128, 4, 8, wf_c0);
  k_wconv<<<8, 256, 0, stream>>>(conv_W + (size_t)HID * HID, 128, 4, 8, wf_c1);
  k_wconv<<<4, 256, 0, stream>>>(dec_W, 64, 4, 4, wf_dec);

  // normalization + CSR build
  k_deg<<<(E + 255) / 256, 256, 0, stream>>>(dst, E, deg);
  k_dinv<<<nb, 256, 0, stream>>>(deg, dinv, N);
  k_scan1<<<nb, 256, 0, stream>>>(deg, N, rowptr, bsum);
  k_scan2<<<1, 256, 0, stream>>>(bsum, boff, nb);
  k_scan3<<<nb, 256, 0, stream>>>(rowptr, boff, N);
  k_fill<<<(E + 255) / 256, 256, 0, stream>>>(src, dst, E, rowptr, cursor, eidx);

  const int gm = (N + 63) / 64;

  // encoder: h = lrelu(x @ enc_W + enc_b)
  k_mfma<8, 0><<<gm, 256, 0, stream>>>(x, wf_enc, enc_b, nullptr, h, N, 256);

  for (int l = 0; l < 2; ++l) {
    const unsigned short* wf = l ? wf_c1 : wf_c0;
    // t = (h @ W) * dinv[row]
    k_mfma<8, 1><<<gm, 256, 0, stream>>>(h, wf, nullptr, dinv, t, N, HID);
    // h[d] = lrelu((sum_e t[src_e] + t[d]) * dinv[d] + b)
    k_gather<<<(N * 32 + 255) / 256, 256, 0, stream>>>(
        rowptr, deg, eidx, t, dinv, conv_b + (size_t)l * HID, h, N);
  }

  // decoder: out = h @ dec_W + dec_b
  k_mfma<4, 2><<<gm, 256, 0, stream>>>(h, wf_dec, dec_b, nullptr, out, N, HID);
}

// Round 4
// 342.726 us; speedup vs baseline: 8.6994x; 1.1719x over previous
//
#include <hip/hip_runtime.h>

// GCN forward: x[50000,256] -> enc(256->128)+lrelu -> 2x GCNConv(128->128)+lrelu -> dec(128->64)
// f32 in/out. GEMMs: bf16 MFMA (16x16x32) with hi/lo split precision (f32-grade).
// Aggregation: CSR-over-dst + gather. t (message matrix) stored bf16 to halve the
// per-XCD compulsory L2-miss traffic (FETCH was exactly 8 XCDs x |t|).

constexpr int HID = 128;
constexpr float NEG = 0.1f;

typedef __attribute__((ext_vector_type(8))) short short8;  // 8 bf16 (4 VGPRs)
typedef __attribute__((ext_vector_type(4))) float f32x4;   // MFMA C/D

__device__ __forceinline__ float lrelu(float v) { return v > 0.f ? v : v * NEG; }

__device__ __forceinline__ unsigned short f2bf(float f) {  // f32 -> bf16, RNE
  union { float f; unsigned u; } c; c.f = f;
  unsigned u = c.u;
  return (unsigned short)((u + 0x7fffu + ((u >> 16) & 1u)) >> 16);
}
__device__ __forceinline__ float bf2f(unsigned short h) {
  union { unsigned u; float f; } c; c.u = ((unsigned)h) << 16; return c.f;
}

// ---- degree ----
__global__ __launch_bounds__(256) void k_deg(const int* __restrict__ dst, int E,
                                             int* __restrict__ deg) {
  int i = blockIdx.x * 256 + threadIdx.x;
  if (i < E) atomicAdd(&deg[dst[i]], 1);
}

// ---- exclusive prefix scan over deg -> rowptr (+dinv fused) ----
__global__ __launch_bounds__(256) void k_scan1(const int* __restrict__ deg, int N,
                                               int* __restrict__ rowptr,
                                               int* __restrict__ bsum,
                                               float* __restrict__ dinv) {
  __shared__ int s[256];
  int i = blockIdx.x * 256 + threadIdx.x;
  int v = (i < N) ? deg[i] : 0;
  s[threadIdx.x] = v;
  __syncthreads();
#pragma unroll
  for (int off = 1; off < 256; off <<= 1) {
    int t = (threadIdx.x >= off) ? s[threadIdx.x - off] : 0;
    __syncthreads();
    s[threadIdx.x] += t;
    __syncthreads();
  }
  if (i < N) {
    rowptr[i] = s[threadIdx.x] - v;            // exclusive
    dinv[i] = rsqrtf((float)v + 1.0f);         // +1 for self-loop
  }
  if (threadIdx.x == 255) bsum[blockIdx.x] = s[255];
}

__global__ __launch_bounds__(256) void k_scan2(const int* __restrict__ bsum,
                                               int* __restrict__ boff, int nb) {
  __shared__ int s[256];
  int i = threadIdx.x;
  int v = (i < nb) ? bsum[i] : 0;
  s[i] = v;
  __syncthreads();
#pragma unroll
  for (int off = 1; off < 256; off <<= 1) {
    int t = (i >= off) ? s[i - off] : 0;
    __syncthreads();
    s[i] += t;
    __syncthreads();
  }
  if (i < nb) boff[i] = s[i] - v;
}

__global__ __launch_bounds__(256) void k_scan3(int* __restrict__ rowptr,
                                               const int* __restrict__ boff, int N) {
  int i = blockIdx.x * 256 + threadIdx.x;
  if (i < N) rowptr[i] += boff[blockIdx.x];
}

// ---- CSR fill ----
__global__ __launch_bounds__(256) void k_fill(const int* __restrict__ src,
                                              const int* __restrict__ dst, int E,
                                              const int* __restrict__ rowptr,
                                              int* __restrict__ cursor,
                                              int* __restrict__ eidx) {
  int e = blockIdx.x * 256 + threadIdx.x;
  if (e >= E) return;
  int d = dst[e];
  int pos = atomicAdd(&cursor[d], 1);
  eidx[rowptr[d] + pos] = src[e];
}

// ---- weight swizzle: W[K][N] f32 -> fragment-ordered bf16 hi|lo ----
__global__ __launch_bounds__(256) void k_wconv(const float* __restrict__ W, int N,
                                               int KS, int NT,
                                               unsigned short* __restrict__ wf) {
  int idx = blockIdx.x * 256 + threadIdx.x;
  int total = KS * NT * 64;
  if (idx >= total) return;
  int lane = idx & 63, tile = idx >> 6;
  int nt = tile % NT, ks = tile / NT;
  int col = nt * 16 + (lane & 15);
  int krow = ks * 32 + (lane >> 4) * 8;
  unsigned short* o = wf + (size_t)idx * 16;
#pragma unroll
  for (int j = 0; j < 8; ++j) {
    float v = W[(size_t)(krow + j) * N + col];
    unsigned short hi = f2bf(v);
    o[j] = hi;
    o[8 + j] = f2bf(v - bf2f(hi));
  }
}

// ---- MFMA GEMM: C[M][NT*16] = A[M][K] @ W (+epilogue), no LDS ----
// MODE 0: C = lrelu(acc + bias)        f32 out (encoder)
// MODE 1: C = bf16(acc * dinv[row])    bf16 out (conv -> t)
// MODE 2: C = acc + bias               f32 out (decoder)
template <int NT, int MODE>
__global__ __launch_bounds__(256) void k_mfma(const float* __restrict__ A,
                                              const unsigned short* __restrict__ wf,
                                              const float* __restrict__ bias,
                                              const float* __restrict__ dinv,
                                              void* __restrict__ Cout, int M, int K) {
  const int N = NT * 16;
  const int wave = threadIdx.x >> 6, lane = threadIdx.x & 63;
  const int q = lane >> 4, c16 = lane & 15;
  const int row0 = blockIdx.x * 64 + wave * 16;
  int arow = row0 + c16;
  if (arow >= M) arow = M - 1;  // clamp: only pollutes OOB C rows, never stored
  const float* ap = A + (size_t)arow * K + q * 8;
  f32x4 acc[NT];
#pragma unroll
  for (int i = 0; i < NT; ++i) acc[i] = (f32x4){0.f, 0.f, 0.f, 0.f};
  const int KS = K >> 5;
  for (int ks = 0; ks < KS; ++ks) {
    float av[8];
    *(float4*)&av[0] = *(const float4*)(ap + ks * 32);
    *(float4*)&av[4] = *(const float4*)(ap + ks * 32 + 4);
    short8 ahi, alo;
#pragma unroll
    for (int j = 0; j < 8; ++j) {
      unsigned short h = f2bf(av[j]);
      ahi[j] = (short)h;
      alo[j] = (short)f2bf(av[j] - bf2f(h));
    }
    const unsigned short* wp = wf + (size_t)ks * NT * 1024 + lane * 16;
#pragma unroll
    for (int nt = 0; nt < NT; ++nt) {
      short8 bhi = *(const short8*)(wp);
      short8 blo = *(const short8*)(wp + 8);
      acc[nt] = __builtin_amdgcn_mfma_f32_16x16x32_bf16(ahi, bhi, acc[nt], 0, 0, 0);
      acc[nt] = __builtin_amdgcn_mfma_f32_16x16x32_bf16(ahi, blo, acc[nt], 0, 0, 0);
      acc[nt] = __builtin_amdgcn_mfma_f32_16x16x32_bf16(alo, bhi, acc[nt], 0, 0, 0);
      wp += 1024;
    }
  }
  // C/D layout (verified m89): col = lane&15, row = (lane>>4)*4 + reg
#pragma unroll
  for (int nt = 0; nt < NT; ++nt) {
    int col = nt * 16 + c16;
    float bv = (MODE == 1) ? 0.f : bias[col];
#pragma unroll
    for (int r = 0; r < 4; ++r) {
      int gr = row0 + q * 4 + r;
      if (gr >= M) continue;
      float v = acc[nt][r];
      if (MODE == 0) {
        ((float*)Cout)[(size_t)gr * N + col] = lrelu(v + bv);
      } else if (MODE == 1) {
        ((unsigned short*)Cout)[(size_t)gr * N + col] = f2bf(v * dinv[gr]);
      } else {
        ((float*)Cout)[(size_t)gr * N + col] = v + bv;
      }
    }
  }
}

// ---- gather aggregation: h[d] = lrelu((sum_e t[src_e] + t[d]) * dinv[d] + b) ----
// t is bf16, pre-scaled by dinv[src]. 16 lanes (8 bf16 each) per node.
__global__ __launch_bounds__(256) void k_gather(const int* __restrict__ rowptr,
                                                const int* __restrict__ deg,
                                                const int* __restrict__ eidx,
                                                const unsigned short* __restrict__ t,
                                                const float* __restrict__ dinv,
                                                const float* __restrict__ bias,
                                                float* __restrict__ h, int N) {
  int node = (blockIdx.x * 256 + threadIdx.x) >> 4;
  int lane = threadIdx.x & 15;
  if (node >= N) return;
  const uint4* t4 = (const uint4*)t;  // 16B = 8 bf16; row stride = 16 uint4
  int beg = rowptr[node];
  int d = deg[node];
  float acc[8] = {};
#define ADDV(v)                                         \
  {                                                     \
    unsigned dw[4] = {(v).x, (v).y, (v).z, (v).w};      \
    _Pragma("unroll") for (int i = 0; i < 4; ++i) {     \
      union { unsigned u; float f; } lo, hi;            \
      lo.u = dw[i] << 16;                               \
      hi.u = dw[i] & 0xffff0000u;                       \
      acc[2 * i] += lo.f;                               \
      acc[2 * i + 1] += hi.f;                           \
    }                                                   \
  }
  int e = 0;
  for (; e + 4 <= d; e += 4) {
    int s0 = eidx[beg + e + 0], s1 = eidx[beg + e + 1];
    int s2 = eidx[beg + e + 2], s3 = eidx[beg + e + 3];
    uint4 v0 = t4[(size_t)s0 * 16 + lane];
    uint4 v1 = t4[(size_t)s1 * 16 + lane];
    uint4 v2 = t4[(size_t)s2 * 16 + lane];
    uint4 v3 = t4[(size_t)s3 * 16 + lane];
    ADDV(v0); ADDV(v1); ADDV(v2); ADDV(v3);
  }
  for (; e < d; ++e) {
    int s = eidx[beg + e];
    uint4 v = t4[(size_t)s * 16 + lane];
    ADDV(v);
  }
  {  // self-loop term
    uint4 vs = t4[(size_t)node * 16 + lane];
    ADDV(vs);
  }
#undef ADDV
  float w = dinv[node];
  float* hp = h + (size_t)node * HID + lane * 8;
  const float* bp = bias + lane * 8;
  float4 o1, o2;
  float* o = (float*)&o1;
#pragma unroll
  for (int i = 0; i < 4; ++i) o[i] = lrelu(acc[i] * w + bp[i]);
  o = (float*)&o2;
#pragma unroll
  for (int i = 0; i < 4; ++i) o[i] = lrelu(acc[4 + i] * w + bp[4 + i]);
  *(float4*)hp = o1;
  *(float4*)(hp + 4) = o2;
}

extern "C" void kernel_launch(void* const* d_in, const int* in_sizes, int n_in,
                              void* d_out, int out_size, void* d_ws, size_t ws_size,
                              hipStream_t stream) {
  const float* x = (const float*)d_in[0];
  const int* ei = (const int*)d_in[1];
  const float* enc_W = (const float*)d_in[2];
  const float* enc_b = (const float*)d_in[3];
  const float* conv_W = (const float*)d_in[4];
  const float* conv_b = (const float*)d_in[5];
  const float* dec_W = (const float*)d_in[6];
  const float* dec_b = (const float*)d_in[7];
  float* out = (float*)d_out;

  const int IN_DIM = 256;
  const int N = in_sizes[0] / IN_DIM;  // 50000
  const int E = in_sizes[1] / 2;       // 800000
  const int* src = ei;
  const int* dst = ei + E;
  const int nb = (N + 255) / 256;

  // workspace layout
  char* wp = (char*)d_ws;
  auto alloc = [&](size_t bytes) {
    void* p = wp;
    wp += (bytes + 255) & ~(size_t)255;
    return p;
  };
  int* deg = (int*)alloc((size_t)N * 4);
  int* cursor = (int*)alloc((size_t)N * 4);  // adjacent to deg: one memset covers both
  int* rowptr = (int*)alloc((size_t)N * 4);
  int* bsum = (int*)alloc(1024);
  int* boff = (int*)alloc(1024);
  int* eidx = (int*)alloc((size_t)E * 4);
  float* dinv = (float*)alloc((size_t)N * 4);
  float* h = (float*)alloc((size_t)N * HID * 4);
  unsigned short* t = (unsigned short*)alloc((size_t)N * HID * 2);  // bf16
  unsigned short* wf_enc = (unsigned short*)alloc((size_t)8 * 8 * 64 * 16 * 2);  // K=256,N=128
  unsigned short* wf_c0 = (unsigned short*)alloc((size_t)4 * 8 * 64 * 16 * 2);   // K=128,N=128
  unsigned short* wf_c1 = (unsigned short*)alloc((size_t)4 * 8 * 64 * 16 * 2);
  unsigned short* wf_dec = (unsigned short*)alloc((size_t)4 * 4 * 64 * 16 * 2);  // K=128,N=64

  // zero deg + cursor (contiguous, each padded to 256B)
  hipMemsetAsync(deg, 0, (((size_t)N * 4 + 255) & ~(size_t)255) * 2, stream);

  // weight swizzles (tiny)
  k_wconv<<<16, 256, 0, stream>>>(enc_W, 128, 8, 8, wf_enc);
  k_wconv<<<8, 256, 0, stream>>>(conv_W, 128, 4, 8, wf_c0);
  k_wconv<<<8, 256, 0, stream>>>(conv_W + (size_t)HID * HID, 128, 4, 8, wf_c1);
  k_wconv<<<4, 256, 0, stream>>>(dec_W, 64, 4, 4, wf_dec);

  // normalization + CSR build
  k_deg<<<(E + 255) / 256, 256, 0, stream>>>(dst, E, deg);
  k_scan1<<<nb, 256, 0, stream>>>(deg, N, rowptr, bsum, dinv);
  k_scan2<<<1, 256, 0, stream>>>(bsum, boff, nb);
  k_scan3<<<nb, 256, 0, stream>>>(rowptr, boff, N);
  k_fill<<<(E + 255) / 256, 256, 0, stream>>>(src, dst, E, rowptr, cursor, eidx);

  const int gm = (N + 63) / 64;

  // encoder: h = lrelu(x @ enc_W + enc_b)
  k_mfma<8, 0><<<gm, 256, 0, stream>>>(x, wf_enc, enc_b, nullptr, h, N, 256);

  for (int l = 0; l < 2; ++l) {
    const unsigned short* wf = l ? wf_c1 : wf_c0;
    // t = bf16((h @ W) * dinv[row])
    k_mfma<8, 1><<<gm, 256, 0, stream>>>(h, wf, nullptr, dinv, t, N, HID);
    // h[d] = lrelu((sum_e t[src_e] + t[d]) * dinv[d] + b)
    k_gather<<<(N * 16 + 255) / 256, 256, 0, stream>>>(
        rowptr, deg, eidx, t, dinv, conv_b + (size_t)l * HID, h, N);
  }

  // decoder: out = h @ dec_W + dec_b
  k_mfma<4, 2><<<gm, 256, 0, stream>>>(h, wf_dec, dec_b, nullptr, out, N, HID);
}